// Round 7
// baseline (744.286 us; speedup 1.0000x reference)
//
#include <hip/hip_runtime.h>
#include <hip/hip_fp16.h>

#define BATCH 16
#define NROW 1024
#define MCOL 1024
#define DFEAT 128

// DP blocking: one wave per batch, 16 rows/thread, 8 cols/phase
#define R_DP 16
#define C_DP 8
#define NCH (MCOL / C_DP)   // 128 chunks along j
#define NPH (NCH + 63)      // 191 phases (loop rounds to 192)

#define L2E 1.4426950408889634f
#define LN2 0.6931471805599453f

typedef __attribute__((ext_vector_type(8))) short short8;
typedef __attribute__((ext_vector_type(4))) float f32x4;

__device__ inline unsigned short f2bf(float f) {  // RNE f32 -> bf16 bits
  unsigned u = __float_as_uint(f);
  return (unsigned short)((u + 0x7fff + ((u >> 16) & 1)) >> 16);
}

// ---------------------------------------------------------------------------
// Kernel 1: normalize rows and emit bf16 copies. One wave per row.
// ---------------------------------------------------------------------------
__global__ __launch_bounds__(256) void norm_kernel(
    const float* __restrict__ x, const float* __restrict__ y,
    unsigned short* __restrict__ xnb, unsigned short* __restrict__ ynb) {
  int row = blockIdx.x * 4 + (threadIdx.x >> 6);
  int lane = threadIdx.x & 63;
  const float* src;
  unsigned short* dst;
  if (row < BATCH * NROW) {
    src = x + (size_t)row * DFEAT;
    dst = xnb + (size_t)row * DFEAT;
  } else {
    int r2 = row - BATCH * NROW;
    src = y + (size_t)r2 * DFEAT;
    dst = ynb + (size_t)r2 * DFEAT;
  }
  float2 v = *(const float2*)(src + lane * 2);
  float s = v.x * v.x + v.y * v.y;
  #pragma unroll
  for (int o = 32; o > 0; o >>= 1) s += __shfl_xor(s, o, 64);
  float inv = 1.0f / (sqrtf(s) + 1e-8f);
  unsigned short b0 = f2bf(v.x * inv), b1 = f2bf(v.y * inv);
  *(unsigned*)(dst + lane * 2) = (unsigned)b0 | ((unsigned)b1 << 16);
}

// ---------------------------------------------------------------------------
// Kernel 2: MFMA distance GEMM, 128x128 tile/block, 4 waves (2x2 of 64x64),
// bf16 16x16x32 MFMA; epilogue stores exp(-(1-dot)) as fp16 row-major.
// LDS XOR-swizzle (byte ^= (row&7)<<4) kills the 16-way LDA bank conflict.
// ---------------------------------------------------------------------------
__global__ __launch_bounds__(256) void dist_kernel(
    const unsigned short* __restrict__ xnb, const unsigned short* __restrict__ ynb,
    __half* __restrict__ Dexp) {
  __shared__ __align__(16) unsigned char xsb[128 * 256];
  __shared__ __align__(16) unsigned char ysb[128 * 256];

  int b = blockIdx.z, ti0 = blockIdx.y, tj0 = blockIdx.x;
  int I0 = ti0 * 128, J0 = tj0 * 128;
  int tid = threadIdx.x;

  const uint4* xsrc = (const uint4*)(xnb + (size_t)(b * NROW + I0) * DFEAT);
  const uint4* ysrc = (const uint4*)(ynb + (size_t)(b * MCOL + J0) * DFEAT);
  #pragma unroll
  for (int it = 0; it < 8; ++it) {
    int idx = tid + it * 256;           // 0..2047: row = idx>>4, 16B col = idx&15
    int row = idx >> 4, cb = (idx & 15) * 16;
    int swz = row * 256 + (cb ^ ((row & 7) << 4));
    *(uint4*)&xsb[swz] = xsrc[idx];
    *(uint4*)&ysb[swz] = ysrc[idx];
  }
  __syncthreads();

  int wid = tid >> 6, lane = tid & 63;
  int wi = wid >> 1, wj = wid & 1;      // 64x64 quadrant
  int lr = lane & 15, lk = lane >> 4;   // frag row = lr, k-group = lk

  f32x4 acc[4][4] = {};
  #pragma unroll
  for (int ks = 0; ks < 4; ++ks) {
    int cb = ks * 64 + lk * 16;
    short8 af[4], bf[4];
    #pragma unroll
    for (int ti = 0; ti < 4; ++ti) {
      int row = wi * 64 + ti * 16 + lr;
      af[ti] = *(short8*)&xsb[row * 256 + (cb ^ ((row & 7) << 4))];
    }
    #pragma unroll
    for (int tj = 0; tj < 4; ++tj) {
      int row = wj * 64 + tj * 16 + lr;
      bf[tj] = *(short8*)&ysb[row * 256 + (cb ^ ((row & 7) << 4))];
    }
    #pragma unroll
    for (int ti = 0; ti < 4; ++ti)
      #pragma unroll
      for (int tj = 0; tj < 4; ++tj)
        acc[ti][tj] = __builtin_amdgcn_mfma_f32_16x16x32_bf16(
            af[ti], bf[tj], acc[ti][tj], 0, 0, 0);
  }

  // epilogue: C/D layout col=lane&15, row=(lane>>4)*4+v
  #pragma unroll
  for (int ti = 0; ti < 4; ++ti) {
    #pragma unroll
    for (int tj = 0; tj < 4; ++tj) {
      int gi = I0 + wi * 64 + ti * 16 + lk * 4;
      int gj = J0 + wj * 64 + tj * 16 + lr;
      #pragma unroll
      for (int v = 0; v < 4; ++v) {
        float d = 1.0f - acc[ti][tj][v];
        Dexp[((size_t)b * NROW + gi + v) * MCOL + gj] = __float2half(exp2f(-d * L2E));
      }
    }
  }
}

// ---------------------------------------------------------------------------
// Kernel 3: wave-autonomous exp-domain soft-DTW DP. One wave per batch:
// thread t owns rows 16t..16t+15; phase p processes chunk c = p - t (8 cols).
// All handoff via shfl_up (intra-wave) -> NO barriers, NO LDS. Ping-pong
// prefetch buffers, loop unrolled x2 so the rotation renames away.
// Math identical to the r5-verified recurrence (E = exp(O - R), renorm
// E *= 2^-ex  =>  O -= ex*ln2).
// ---------------------------------------------------------------------------
__device__ inline void unpack8(uint4 v, float* e) {
  const __half2* h = reinterpret_cast<const __half2*>(&v);
  #pragma unroll
  for (int q = 0; q < 4; ++q) {
    float2 f = __half22float2(h[q]);
    e[2 * q] = f.x;
    e[2 * q + 1] = f.y;
  }
}

#define DTW_STEP(P, CUR, NXT)                                                \
  {                                                                          \
    int c = (P) - t;                                                         \
    _Pragma("unroll")                                                        \
    for (int r = 0; r < R_DP; ++r) {                                         \
      int cc = (c + 1) < 0 ? 0 : ((c + 1) >= NCH ? NCH - 1 : (c + 1));       \
      NXT[r] = *reinterpret_cast<const uint4*>(Db + (size_t)r * MCOL +       \
                                               cc * C_DP);                   \
    }                                                                        \
    float U[C_DP + 1];                                                       \
    _Pragma("unroll")                                                        \
    for (int k = 0; k <= C_DP; ++k) U[k] = __shfl_up(B[k], 1, 64);           \
    float Oin = __shfl_up(O, 1, 64);                                         \
    if (t == 0) {                                                            \
      _Pragma("unroll")                                                      \
      for (int k = 0; k <= C_DP; ++k) U[k] = 0.0f;                           \
      U[0] = (c == 0) ? 1.0f : 0.0f;                                         \
      Oin = O;                                                               \
    }                                                                        \
    if (c >= 0 && c < NCH) {                                                 \
      if (c == 0) O = Oin;                                                   \
      float sc = exp2f((O - Oin) * L2E);                                     \
      _Pragma("unroll")                                                      \
      for (int k = 0; k <= C_DP; ++k) U[k] *= sc;                            \
      _Pragma("unroll")                                                      \
      for (int r = 0; r < R_DP; ++r) {                                       \
        float e[C_DP];                                                       \
        unpack8(CUR[r], e);                                                  \
        float A[C_DP];                                                       \
        _Pragma("unroll")                                                    \
        for (int k = 0; k < C_DP; ++k) A[k] = e[k] * (U[k] + U[k + 1]);      \
        float oldc = carry[r];                                               \
        float left = oldc;                                                   \
        float V[C_DP];                                                       \
        _Pragma("unroll")                                                    \
        for (int k = 0; k < C_DP; ++k) {                                     \
          left = fmaf(e[k], left, A[k]);                                     \
          V[k] = left;                                                       \
        }                                                                    \
        U[0] = oldc;                                                         \
        _Pragma("unroll")                                                    \
        for (int k = 1; k <= C_DP; ++k) U[k] = V[k - 1];                     \
        carry[r] = V[C_DP - 1];                                              \
      }                                                                      \
      float rep = carry[R_DP - 1];                                           \
      if (rep > 0.0f) {                                                      \
        int ex = (int)((__float_as_uint(rep) >> 23) & 0xFF) - 127;           \
        if ((ex < -8 || ex > 8) && ex < 128) {                               \
          float s = __uint_as_float((unsigned)(127 - ex) << 23);             \
          _Pragma("unroll")                                                  \
          for (int r = 0; r < R_DP; ++r) carry[r] *= s;                      \
          _Pragma("unroll")                                                  \
          for (int k = 0; k <= C_DP; ++k) U[k] *= s;                         \
          O -= (float)ex * LN2;                                              \
        }                                                                    \
      }                                                                      \
      _Pragma("unroll")                                                      \
      for (int k = 0; k <= C_DP; ++k) B[k] = U[k];                           \
    }                                                                        \
  }

__global__ __launch_bounds__(256, 1) void dtw_kernel(
    const __half* __restrict__ Dexp, float* __restrict__ out) {
  int wv = threadIdx.x >> 6;
  int b = blockIdx.x * 4 + wv;          // wave = batch
  int t = threadIdx.x & 63;             // thread-in-batch

  const __half* Db = Dexp + ((size_t)b * NROW + (size_t)t * R_DP) * MCOL;

  float carry[R_DP];
  #pragma unroll
  for (int r = 0; r < R_DP; ++r) carry[r] = 0.0f;
  float B[C_DP + 1] = {};
  float O = 0.0f;

  uint4 bufA[R_DP], bufB[R_DP];
  #pragma unroll
  for (int r = 0; r < R_DP; ++r) {
    int cc = (0 - t) < 0 ? 0 : (0 - t);
    bufA[r] = *reinterpret_cast<const uint4*>(Db + (size_t)r * MCOL + cc * C_DP);
  }

  for (int p = 0; p < NPH; p += 2) {
    DTW_STEP(p, bufA, bufB);
    DTW_STEP(p + 1, bufB, bufA);
  }

  if (t == 63) out[b] = O - logf(carry[R_DP - 1]);  // R[N][M]
}

// ---------------------------------------------------------------------------
extern "C" void kernel_launch(void* const* d_in, const int* in_sizes, int n_in,
                              void* d_out, int out_size, void* d_ws, size_t ws_size,
                              hipStream_t stream) {
  const float* x = (const float*)d_in[0];
  const float* y = (const float*)d_in[1];
  float* out = (float*)d_out;

  char* ws = (char*)d_ws;
  __half* Dexp = (__half*)ws;
  size_t dd_bytes = (size_t)BATCH * NROW * MCOL * sizeof(__half);  // 33.5 MB
  unsigned short* xnb = (unsigned short*)(ws + dd_bytes);          // 4 MB
  unsigned short* ynb = xnb + (size_t)BATCH * NROW * DFEAT;        // 4 MB

  norm_kernel<<<(2 * BATCH * NROW) / 4, 256, 0, stream>>>(x, y, xnb, ynb);
  dist_kernel<<<dim3(MCOL / 128, NROW / 128, BATCH), 256, 0, stream>>>(
      xnb, ynb, Dexp);
  dtw_kernel<<<BATCH / 4, 256, 0, stream>>>(Dexp, out);
}

// Round 8
// 346.638 us; speedup vs baseline: 2.1472x; 2.1472x over previous
//
#include <hip/hip_runtime.h>
#include <hip/hip_fp16.h>

#define BATCH 16
#define NROW 1024
#define MCOL 1024
#define DFEAT 128

// DP blocking: one wave per batch, 16 rows/thread, 8 cols/phase
#define R_DP 16
#define C_DP 8
#define NCH (MCOL / C_DP)   // 128 chunks along j
#define NPH (NCH + 63)      // 191 phases

#define L2E 1.4426950408889634f
#define LN2 0.6931471805599453f

typedef __attribute__((ext_vector_type(8))) short short8;
typedef __attribute__((ext_vector_type(4))) float f32x4;

__device__ inline unsigned short f2bf(float f) {  // RNE f32 -> bf16 bits
  unsigned u = __float_as_uint(f);
  return (unsigned short)((u + 0x7fff + ((u >> 16) & 1)) >> 16);
}

// ---------------------------------------------------------------------------
// Kernel 1: normalize rows and emit bf16 copies. One wave per row.
// ---------------------------------------------------------------------------
__global__ __launch_bounds__(256) void norm_kernel(
    const float* __restrict__ x, const float* __restrict__ y,
    unsigned short* __restrict__ xnb, unsigned short* __restrict__ ynb) {
  int row = blockIdx.x * 4 + (threadIdx.x >> 6);
  int lane = threadIdx.x & 63;
  const float* src;
  unsigned short* dst;
  if (row < BATCH * NROW) {
    src = x + (size_t)row * DFEAT;
    dst = xnb + (size_t)row * DFEAT;
  } else {
    int r2 = row - BATCH * NROW;
    src = y + (size_t)r2 * DFEAT;
    dst = ynb + (size_t)r2 * DFEAT;
  }
  float2 v = *(const float2*)(src + lane * 2);
  float s = v.x * v.x + v.y * v.y;
  #pragma unroll
  for (int o = 32; o > 0; o >>= 1) s += __shfl_xor(s, o, 64);
  float inv = 1.0f / (sqrtf(s) + 1e-8f);
  unsigned short b0 = f2bf(v.x * inv), b1 = f2bf(v.y * inv);
  *(unsigned*)(dst + lane * 2) = (unsigned)b0 | ((unsigned)b1 << 16);
}

// ---------------------------------------------------------------------------
// Kernel 2: MFMA distance GEMM, 128x128 tile/block, 4 waves (2x2 of 64x64),
// bf16 16x16x32 MFMA; epilogue stores exp(-(1-dot)) as fp16 row-major.
// LDS XOR-swizzle (byte ^= (row&7)<<4) kills the 16-way LDA bank conflict.
// ---------------------------------------------------------------------------
__global__ __launch_bounds__(256) void dist_kernel(
    const unsigned short* __restrict__ xnb, const unsigned short* __restrict__ ynb,
    __half* __restrict__ Dexp) {
  __shared__ __align__(16) unsigned char xsb[128 * 256];
  __shared__ __align__(16) unsigned char ysb[128 * 256];

  int b = blockIdx.z, ti0 = blockIdx.y, tj0 = blockIdx.x;
  int I0 = ti0 * 128, J0 = tj0 * 128;
  int tid = threadIdx.x;

  const uint4* xsrc = (const uint4*)(xnb + (size_t)(b * NROW + I0) * DFEAT);
  const uint4* ysrc = (const uint4*)(ynb + (size_t)(b * MCOL + J0) * DFEAT);
  #pragma unroll
  for (int it = 0; it < 8; ++it) {
    int idx = tid + it * 256;           // 0..2047: row = idx>>4, 16B col = idx&15
    int row = idx >> 4, cb = (idx & 15) * 16;
    int swz = row * 256 + (cb ^ ((row & 7) << 4));
    *(uint4*)&xsb[swz] = xsrc[idx];
    *(uint4*)&ysb[swz] = ysrc[idx];
  }
  __syncthreads();

  int wid = tid >> 6, lane = tid & 63;
  int wi = wid >> 1, wj = wid & 1;      // 64x64 quadrant
  int lr = lane & 15, lk = lane >> 4;   // frag row = lr, k-group = lk

  f32x4 acc[4][4] = {};
  #pragma unroll
  for (int ks = 0; ks < 4; ++ks) {
    int cb = ks * 64 + lk * 16;
    short8 af[4], bf[4];
    #pragma unroll
    for (int ti = 0; ti < 4; ++ti) {
      int row = wi * 64 + ti * 16 + lr;
      af[ti] = *(short8*)&xsb[row * 256 + (cb ^ ((row & 7) << 4))];
    }
    #pragma unroll
    for (int tj = 0; tj < 4; ++tj) {
      int row = wj * 64 + tj * 16 + lr;
      bf[tj] = *(short8*)&ysb[row * 256 + (cb ^ ((row & 7) << 4))];
    }
    #pragma unroll
    for (int ti = 0; ti < 4; ++ti)
      #pragma unroll
      for (int tj = 0; tj < 4; ++tj)
        acc[ti][tj] = __builtin_amdgcn_mfma_f32_16x16x32_bf16(
            af[ti], bf[tj], acc[ti][tj], 0, 0, 0);
  }

  // epilogue: C/D layout col=lane&15, row=(lane>>4)*4+v
  #pragma unroll
  for (int ti = 0; ti < 4; ++ti) {
    #pragma unroll
    for (int tj = 0; tj < 4; ++tj) {
      int gi = I0 + wi * 64 + ti * 16 + lk * 4;
      int gj = J0 + wj * 64 + tj * 16 + lr;
      #pragma unroll
      for (int v = 0; v < 4; ++v) {
        float d = 1.0f - acc[ti][tj][v];
        Dexp[((size_t)b * NROW + gi + v) * MCOL + gj] = __float2half(exp2f(-d * L2E));
      }
    }
  }
}

// ---------------------------------------------------------------------------
// Kernel 3: wave-autonomous exp-domain soft-DTW DP. One 64-lane wave (=one
// block, one CU) per batch: thread t owns rows 16t..16t+15; phase p handles
// chunk c = p - t (8 cols). Handoff via shfl_up only — no barriers, no LDS.
// SINGLE prefetch buffer with reload-after-consume (r7's ping-pong needed
// ~190 live VGPRs -> regalloc capped 92 -> scratch spill -> 2x regression).
// Math identical to the r5-verified recurrence (E = exp(O - R); renorm
// E *= 2^-ex  =>  O -= ex*ln2).
// ---------------------------------------------------------------------------
__device__ inline void unpack8(uint4 v, float* e) {
  const __half2* h = reinterpret_cast<const __half2*>(&v);
  #pragma unroll
  for (int q = 0; q < 4; ++q) {
    float2 f = __half22float2(h[q]);
    e[2 * q] = f.x;
    e[2 * q + 1] = f.y;
  }
}

__global__ __launch_bounds__(64, 1) void dtw_kernel(
    const __half* __restrict__ Dexp, float* __restrict__ out) {
  int b = blockIdx.x;
  int t = threadIdx.x;                  // 0..63, thread-in-batch

  const __half* Db = Dexp + ((size_t)b * NROW + (size_t)t * R_DP) * MCOL;

  float carry[R_DP];
  #pragma unroll
  for (int r = 0; r < R_DP; ++r) carry[r] = 0.0f;
  float B[C_DP + 1] = {};
  float O = 0.0f;

  // init: chunk 0 for every thread (thread t consumes it at phase p = t)
  uint4 cur[R_DP];
  #pragma unroll
  for (int r = 0; r < R_DP; ++r)
    cur[r] = *reinterpret_cast<const uint4*>(Db + (size_t)r * MCOL);

  for (int p = 0; p < NPH; ++p) {
    int c = p - t;

    float U[C_DP + 1];
    #pragma unroll
    for (int k = 0; k <= C_DP; ++k) U[k] = __shfl_up(B[k], 1, 64);
    float Oin = __shfl_up(O, 1, 64);
    if (t == 0) {
      #pragma unroll
      for (int k = 0; k <= C_DP; ++k) U[k] = 0.0f;
      U[0] = (c == 0) ? 1.0f : 0.0f;    // E[0][0] = exp(-0)
      Oin = O;
    }

    if (c >= 0 && c < NCH) {
      if (c == 0) O = Oin;              // adopt neighbor's frame at activation
      float sc = exp2f((O - Oin) * L2E);
      #pragma unroll
      for (int k = 0; k <= C_DP; ++k) U[k] *= sc;

      int cn = (c + 1 < NCH) ? c + 1 : NCH - 1;
      const __half* nsrc = Db + cn * C_DP;

      #pragma unroll
      for (int r = 0; r < R_DP; ++r) {
        float e[C_DP];
        unpack8(cur[r], e);
        // reload-after-consume: fetch phase p+1's chunk into the same reg
        cur[r] = *reinterpret_cast<const uint4*>(nsrc + (size_t)r * MCOL);
        float A[C_DP];
        #pragma unroll
        for (int k = 0; k < C_DP; ++k) A[k] = e[k] * (U[k] + U[k + 1]);
        float oldc = carry[r];
        float left = oldc;
        float V[C_DP];
        #pragma unroll
        for (int k = 0; k < C_DP; ++k) {
          left = fmaf(e[k], left, A[k]);  // E = expd*(Eup+Eupleft+Eleft)
          V[k] = left;
        }
        U[0] = oldc;
        #pragma unroll
        for (int k = 1; k <= C_DP; ++k) U[k] = V[k - 1];
        carry[r] = V[C_DP - 1];
      }

      // renormalize via exponent bits (E *= 2^-ex  =>  O -= ex*ln2)
      float rep = carry[R_DP - 1];
      if (rep > 0.0f) {
        int ex = (int)((__float_as_uint(rep) >> 23) & 0xFF) - 127;
        if ((ex < -8 || ex > 8) && ex < 128) {
          float s = __uint_as_float((unsigned)(127 - ex) << 23);  // 2^-ex
          #pragma unroll
          for (int r = 0; r < R_DP; ++r) carry[r] *= s;
          #pragma unroll
          for (int k = 0; k <= C_DP; ++k) U[k] *= s;
          O -= (float)ex * LN2;
        }
      }
      #pragma unroll
      for (int k = 0; k <= C_DP; ++k) B[k] = U[k];
    }
  }

  if (t == 63) out[b] = O - logf(carry[R_DP - 1]);  // R[N][M]
}

// ---------------------------------------------------------------------------
extern "C" void kernel_launch(void* const* d_in, const int* in_sizes, int n_in,
                              void* d_out, int out_size, void* d_ws, size_t ws_size,
                              hipStream_t stream) {
  const float* x = (const float*)d_in[0];
  const float* y = (const float*)d_in[1];
  float* out = (float*)d_out;

  char* ws = (char*)d_ws;
  __half* Dexp = (__half*)ws;
  size_t dd_bytes = (size_t)BATCH * NROW * MCOL * sizeof(__half);  // 33.5 MB
  unsigned short* xnb = (unsigned short*)(ws + dd_bytes);          // 4 MB
  unsigned short* ynb = xnb + (size_t)BATCH * NROW * DFEAT;        // 4 MB

  norm_kernel<<<(2 * BATCH * NROW) / 4, 256, 0, stream>>>(x, y, xnb, ynb);
  dist_kernel<<<dim3(MCOL / 128, NROW / 128, BATCH), 256, 0, stream>>>(
      xnb, ynb, Dexp);
  dtw_kernel<<<BATCH, 64, 0, stream>>>(Dexp, out);
}